// Round 1
// baseline (295.101 us; speedup 1.0000x reference)
//
#include <hip/hip_runtime.h>

// DropBlock + LIF forward, two kernels (bit-packed masks).
// x: [T*bs, C, H, W] = [160, 64, 64, 64] f32, mask_rand: [160, 64, 64] f32
// out: [160, 64, 64, 64] f32
//
// Stage 1 (bm_bits_kernel): per row (one wave each), dropblock row-mask as a
//   64-bit word: 7 clipped vertical loads/lane -> OR -> __ballot (vertical
//   dilate) -> bit smear +/-3 (horizontal dilate). Set bit = dropped.
//   Output: 10240 x uint64 = 80 KB in d_ws (L1/L2-resident for stage 2).
// Stage 2 (lif_kernel): linear-index float4 streaming, grid-stride (2048
//   blocks, guideline-11 shape), PLAIN loads/stores (R4: NT hints removed —
//   m13's 6.29 TB/s copy ceiling uses plain cached float4 ops; NT measured
//   as the suspect for lif sitting at ~4.6 TB/s).
//   u = (u>1 ? 0 : 0.5u) + x_t (bitwise equal to tau*u*(1-spike)+x),
//   o_t = (u>1 && !dropped) ? 1 : 0. Per-t mask is one 8 B load (4 distinct
//   addresses per wave -> broadcast, cache-hot).

#define TSTEPS 5
#define BSZ 32
#define CHN 64
#define HH 64
#define WW 64

typedef float v4f __attribute__((ext_vector_type(4)));

__global__ __launch_bounds__(256) void bm_bits_kernel(const float* __restrict__ mr,
                                                      unsigned long long* __restrict__ bmbits) {
    // one wave (64 lanes) per row; 4 waves per block; rows = T*bs*HH = 10240
    const float GAMMA = (float)(0.1 / 49.0);  // matches JAX weak-type promotion
    int row = blockIdx.x * 4 + (threadIdx.x >> 6);  // [0, 10240)
    int lane = threadIdx.x & 63;                    // pixel w
    int h = row & (HH - 1);
    int n = row >> 6;  // plane id in [0, T*bs)

    const float* base = mr + (size_t)n * (HH * WW) + lane;
    bool drop = false;
#pragma unroll
    for (int dh = -3; dh <= 3; ++dh) {
        int hh = h + dh;
        if (hh >= 0 && hh < HH) drop = drop || (base[hh * WW] < GAMMA);
    }
    unsigned long long m = __ballot(drop);  // bit w = column drop (vertical done)
    unsigned long long s = m | (m << 1) | (m << 2) | (m << 3)
                             | (m >> 1) | (m >> 2) | (m >> 3);
    if (lane == 0) bmbits[row] = s;  // set bit => dropped => output 0
}

__global__ __launch_bounds__(256) void lif_kernel(const float* __restrict__ x,
                                                  const unsigned long long* __restrict__ bmbits,
                                                  float* __restrict__ o) {
    const int HW4 = HH * WW / 4;          // 1024 float4 groups per plane
    const int TOT = BSZ * CHN * HW4;      // 2,097,152 float4 groups per time step
    const size_t XT = (size_t)BSZ * CHN * HH * WW;  // x/o time stride (floats)
    const int MT = BSZ * HH;              // bmbits time stride (rows)

    int stride = gridDim.x * blockDim.x;
    for (int idx = blockIdx.x * blockDim.x + threadIdx.x; idx < TOT; idx += stride) {
        int hw4 = idx & (HW4 - 1);
        int c = (idx >> 10) & (CHN - 1);
        int b = idx >> 16;

        int h = hw4 >> 4;     // row within plane
        int sh = (hw4 & 15) * 4;

        size_t xoff = (((size_t)b * CHN + c) * (size_t)(HH * WW)) + (size_t)hw4 * 4;
        int mrow = b * HH + h;  // + t*BSZ*HH per step

        v4f u = {0.f, 0.f, 0.f, 0.f};
#pragma unroll
        for (int t = 0; t < TSTEPS; ++t) {
            v4f xv = *(const v4f*)(x + xoff + (size_t)t * XT);
            unsigned int nib = (unsigned int)((bmbits[mrow + t * MT] >> sh) & 0xFull);
            u.x = (u.x > 1.0f ? 0.0f : 0.5f * u.x) + xv.x;
            u.y = (u.y > 1.0f ? 0.0f : 0.5f * u.y) + xv.y;
            u.z = (u.z > 1.0f ? 0.0f : 0.5f * u.z) + xv.z;
            u.w = (u.w > 1.0f ? 0.0f : 0.5f * u.w) + xv.w;
            v4f ov;
            ov.x = (u.x > 1.0f && !(nib & 1u)) ? 1.0f : 0.0f;
            ov.y = (u.y > 1.0f && !(nib & 2u)) ? 1.0f : 0.0f;
            ov.z = (u.z > 1.0f && !(nib & 4u)) ? 1.0f : 0.0f;
            ov.w = (u.w > 1.0f && !(nib & 8u)) ? 1.0f : 0.0f;
            *(v4f*)(o + xoff + (size_t)t * XT) = ov;
        }
    }
}

extern "C" void kernel_launch(void* const* d_in, const int* in_sizes, int n_in,
                              void* d_out, int out_size, void* d_ws, size_t ws_size,
                              hipStream_t stream) {
    const float* x = (const float*)d_in[0];
    const float* mask_rand = (const float*)d_in[1];
    float* out = (float*)d_out;
    unsigned long long* bmbits = (unsigned long long*)d_ws;  // 10240 * 8 B = 80 KB

    const int bm_rows = TSTEPS * BSZ * HH;  // 10240 rows (1 wave each)

    bm_bits_kernel<<<bm_rows / 4, 256, 0, stream>>>(mask_rand, bmbits);
    lif_kernel<<<2048, 256, 0, stream>>>(x, bmbits, out);
}